// Round 7
// baseline (25.953 us; speedup 1.0000x reference)
//
#include <hip/hip_runtime.h>

#define NC      4
#define TPB     256
#define CHUNK_W 256                    // walkers per chunk
#define CHUNK_B (CHUNK_W * 48)         // 12288 bytes = 12 regions of 1024B
#define CHUNK_Q (CHUNK_W * 3)          // 768 float4 per chunk

__global__ __launch_bounds__(TPB) void wvfn_kernel(
    const float* __restrict__ Rs,   // [W,4,3] f32
    const float* __restrict__ A,    // [4] f32
    const float* __restrict__ C,    // [4] f32 (complex64 -> real f32 by harness)
    float* __restrict__ out,        // [W f32] ++ [W f32]
    int W, int nchunks)
{
    __shared__ float4 sh[2 * CHUNK_Q];      // 2 x 12 KB double buffer

    const int t    = threadIdx.x;
    const int lane = t & 63;
    const int wv   = t >> 6;                // wave 0..3
    const size_t total_b = (size_t)W * 48;  // 96e6 (multiple of 1024)
    const char*  gbase   = (const char*)Rs;

    // ---- stage chunk c into buffer b: 3 x global_load_lds_dwordx4 per wave ----
    // LDS is a linear copy of the chunk's 12KB; wave wv owns regions {wv, 4+wv, 8+wv}.
    auto stage = [&](int b, int c) {
        const size_t cb = (size_t)c * CHUNK_B;
        #pragma unroll
        for (int k = 0; k < 3; ++k) {
            const int    r  = k * 4 + wv;                   // region 0..11
            const size_t go = cb + (size_t)r * 1024;
            if (go < total_b) {                             // regions are whole-1KB
                const char* gp = gbase + go + (size_t)lane * 16;   // per-lane global
                char*       lp = (char*)sh + (size_t)b * CHUNK_B + (size_t)r * 1024; // wave-uniform LDS base
                __builtin_amdgcn_global_load_lds(
                    (const __attribute__((address_space(1))) void*)gp,
                    (__attribute__((address_space(3))) void*)lp,
                    16, 0, 0);
            }
        }
    };
    // does this wave issue all 3 loads for chunk c? (region 8+wv exists)
    auto full3 = [&](int c) -> bool {
        return (size_t)c * CHUNK_B + (size_t)(8 + wv) * 1024 < total_b;
    };

    // ---- uniform ansatz coefficients (scalar loads, overlap with staging) ----
    float invA[NC], lap1[NC], lap2[NC], cre[NC];
    #pragma unroll
    for (int n = 0; n < NC; ++n) {
        float ia = 1.0f / A[n];
        invA[n] = ia;
        lap1[n] = (float)NC * ia * ia;
        lap2[n] = 2.0f * ia;
        cre[n]  = C[n];
    }

    const int c0     = blockIdx.x;
    const int stride = gridDim.x;
    int cur = 0;

    if (c0 < nchunks) stage(0, c0);

    for (int c = c0; c < nchunks; c += stride) {
        const int nxt = c + stride;
        const bool have_nxt = (nxt < nchunks);
        if (have_nxt) stage(cur ^ 1, nxt);

        // wait for CURRENT chunk's loads only; keep next chunk's 3 in flight.
        if (have_nxt && full3(nxt)) asm volatile("s_waitcnt vmcnt(3)" ::: "memory");
        else                        asm volatile("s_waitcnt vmcnt(0)" ::: "memory");
        __builtin_amdgcn_s_barrier();       // raw barrier: no compiler vmcnt(0) drain

        const int w = c * CHUNK_W + t;
        if (w < W) {
            const int base = cur * CHUNK_Q + 3 * t;   // byte 48t: conflict-free b128 reads
            float4 q0 = sh[base + 0];
            float4 q1 = sh[base + 1];
            float4 q2 = sh[base + 2];

            float x0 = q0.x, y0 = q0.y, z0 = q0.z;
            float x1 = q0.w, y1 = q1.x, z1 = q1.y;
            float x2 = q1.z, y2 = q1.w, z2 = q2.x;
            float x3 = q2.y, y3 = q2.z, z3 = q2.w;

            float d0 = x0*x0 + y0*y0 + z0*z0;
            float d1 = x1*x1 + y1*y1 + z1*z1;
            float d2 = x2*x2 + y2*y2 + z2*z2;
            float d3 = x3*x3 + y3*y3 + z3*z3;

            float i0 = rsqrtf(d0), i1 = rsqrtf(d1), i2 = rsqrtf(d2), i3 = rsqrtf(d3);
            float r_sum    = d0*i0 + d1*i1 + d2*i2 + d3*i3;
            float invr_sum = i0 + i1 + i2 + i3;

            float V;
            {
                float dx, dy, dz, dd, s = 0.0f;
                dx = x0-x1; dy = y0-y1; dz = z0-z1; dd = dx*dx+dy*dy+dz*dz; s += rsqrtf(dd);
                dx = x0-x2; dy = y0-y2; dz = z0-z2; dd = dx*dx+dy*dy+dz*dz; s += rsqrtf(dd);
                dx = x0-x3; dy = y0-y3; dz = z0-z3; dd = dx*dx+dy*dy+dz*dz; s += rsqrtf(dd);
                dx = x1-x2; dy = y1-y2; dz = z1-z2; dd = dx*dx+dy*dy+dz*dz; s += rsqrtf(dd);
                dx = x1-x3; dy = y1-y3; dz = z1-z3; dd = dx*dx+dy*dy+dz*dz; s += rsqrtf(dd);
                dx = x2-x3; dy = y2-y3; dz = z2-z3; dd = dx*dx+dy*dy+dz*dz; s += rsqrtf(dd);
                V = -s;
            }

            float psi = 0.0f, nab = 0.0f;
            #pragma unroll
            for (int n = 0; n < NC; ++n) {
                float e   = expf(-r_sum * invA[n]);
                float lap = lap1[n] - lap2[n] * invr_sum;
                psi += cre[n] * e;
                nab += cre[n] * e * lap;
            }

            float H = -0.5f * nab + V * psi;
            __builtin_nontemporal_store(psi * H,   &out[w]);
            __builtin_nontemporal_store(psi * psi, &out[(size_t)W + w]);
        }

        __builtin_amdgcn_s_barrier();       // all reads of buf[cur] done before restage
        cur ^= 1;
    }
}

extern "C" void kernel_launch(void* const* d_in, const int* in_sizes, int n_in,
                              void* d_out, int out_size, void* d_ws, size_t ws_size,
                              hipStream_t stream) {
    const float* Rs = (const float*)d_in[0];
    const float* A  = (const float*)d_in[1];
    const float* C  = (const float*)d_in[2];
    float* out = (float*)d_out;

    int W = in_sizes[0] / 12;                       // [W,4,3]
    int nchunks = (W + CHUNK_W - 1) / CHUNK_W;      // 7813 for W=2e6
    int grid = 1536;                                // 6 blocks/CU x 256 CU (24KB LDS each)
    if (grid > nchunks) grid = nchunks;
    wvfn_kernel<<<grid, TPB, 0, stream>>>(Rs, A, C, out, W, nchunks);
}

// Round 8
// 25.626 us; speedup vs baseline: 1.0127x; 1.0127x over previous
//
#include <hip/hip_runtime.h>

#define NC      4
#define TPB     256
#define CHUNK_W 256                    // walkers per block
#define CHUNK_B (CHUNK_W * 48)         // 12288 B = 12 regions of 1024 B
#define CHUNK_Q (CHUNK_W * 3)          // 768 float4

__global__ __launch_bounds__(TPB) void wvfn_kernel(
    const float* __restrict__ Rs,   // [W,4,3] f32
    const float* __restrict__ A,    // [4] f32
    const float* __restrict__ C,    // [4] f32 (complex64 -> real f32 by harness)
    float* __restrict__ out,        // [W f32] ++ [W f32]
    int W)
{
    __shared__ float4 sh[CHUNK_Q];      // 12 KB linear copy of this block's chunk

    const int t    = threadIdx.x;
    const int lane = t & 63;
    const int wv   = t >> 6;            // wave 0..3
    const size_t total_b = (size_t)W * 48;
    const size_t blkbase = (size_t)blockIdx.x * CHUNK_B;
    const char*  gbase   = (const char*)Rs;

    // ---- stage 12 KB via global_load_lds DMA: wave wv owns regions {wv, 4+wv, 8+wv} ----
    // (wave-uniform LDS base + lane*16 — linear layout per m104 constraint)
    #pragma unroll
    for (int k = 0; k < 3; ++k) {
        const int    r  = k * 4 + wv;
        const size_t go = blkbase + (size_t)r * 1024;
        if (go < total_b) {
            const char* gp = gbase + go + (size_t)lane * 16;
            char*       lp = (char*)sh + (size_t)r * 1024;
            __builtin_amdgcn_global_load_lds(
                (const __attribute__((address_space(1))) void*)gp,
                (__attribute__((address_space(3))) void*)lp,
                16, 0, 0);
        }
    }

    // ---- uniform ansatz coefficients (scalar path, overlaps DMA) ----
    float invA[NC], lap1[NC], lap2[NC], cre[NC];
    #pragma unroll
    for (int n = 0; n < NC; ++n) {
        float ia = 1.0f / A[n];
        invA[n] = ia;
        lap1[n] = (float)NC * ia * ia;
        lap2[n] = 2.0f * ia;
        cre[n]  = C[n];
    }

    __syncthreads();    // drains vmcnt(0) — required before consuming DMA'd LDS

    const int w = blockIdx.x * CHUNK_W + t;
    if (w >= W) return;

    // byte 48t: lanes 0-7 sweep all 32 banks once per b128 -> conflict-free
    float4 q0 = sh[3 * t + 0];
    float4 q1 = sh[3 * t + 1];
    float4 q2 = sh[3 * t + 2];

    float x0 = q0.x, y0 = q0.y, z0 = q0.z;
    float x1 = q0.w, y1 = q1.x, z1 = q1.y;
    float x2 = q1.z, y2 = q1.w, z2 = q2.x;
    float x3 = q2.y, y3 = q2.z, z3 = q2.w;

    float d0 = x0*x0 + y0*y0 + z0*z0;
    float d1 = x1*x1 + y1*y1 + z1*z1;
    float d2 = x2*x2 + y2*y2 + z2*z2;
    float d3 = x3*x3 + y3*y3 + z3*z3;

    float i0 = rsqrtf(d0), i1 = rsqrtf(d1), i2 = rsqrtf(d2), i3 = rsqrtf(d3);
    float r_sum    = d0*i0 + d1*i1 + d2*i2 + d3*i3;
    float invr_sum = i0 + i1 + i2 + i3;

    // all-pairs Coulomb (VB = 1)
    float V;
    {
        float dx, dy, dz, dd, s = 0.0f;
        dx = x0-x1; dy = y0-y1; dz = z0-z1; dd = dx*dx+dy*dy+dz*dz; s += rsqrtf(dd);
        dx = x0-x2; dy = y0-y2; dz = z0-z2; dd = dx*dx+dy*dy+dz*dz; s += rsqrtf(dd);
        dx = x0-x3; dy = y0-y3; dz = z0-z3; dd = dx*dx+dy*dy+dz*dz; s += rsqrtf(dd);
        dx = x1-x2; dy = y1-y2; dz = z1-z2; dd = dx*dx+dy*dy+dz*dz; s += rsqrtf(dd);
        dx = x1-x3; dy = y1-y3; dz = z1-z3; dd = dx*dx+dy*dy+dz*dz; s += rsqrtf(dd);
        dx = x2-x3; dy = y2-y3; dz = z2-z3; dd = dx*dx+dy*dy+dz*dz; s += rsqrtf(dd);
        V = -s;
    }

    // psi, nabla_psi (C real)
    float psi = 0.0f, nab = 0.0f;
    #pragma unroll
    for (int n = 0; n < NC; ++n) {
        float e   = expf(-r_sum * invA[n]);
        float lap = lap1[n] - lap2[n] * invr_sum;
        psi += cre[n] * e;
        nab += cre[n] * e * lap;
    }

    float H = -0.5f * nab + V * psi;

    __builtin_nontemporal_store(psi * H,   &out[w]);
    __builtin_nontemporal_store(psi * psi, &out[(size_t)W + w]);
}

extern "C" void kernel_launch(void* const* d_in, const int* in_sizes, int n_in,
                              void* d_out, int out_size, void* d_ws, size_t ws_size,
                              hipStream_t stream) {
    const float* Rs = (const float*)d_in[0];
    const float* A  = (const float*)d_in[1];
    const float* C  = (const float*)d_in[2];
    float* out = (float*)d_out;

    int W = in_sizes[0] / 12;                       // [W,4,3]
    int grid = (W + CHUNK_W - 1) / CHUNK_W;         // 7813 for W=2e6
    wvfn_kernel<<<grid, TPB, 0, stream>>>(Rs, A, C, out, W);
}